// Round 5
// baseline (20994.962 us; speedup 1.0000x reference)
//
#include <hip/hip_runtime.h>
#include <math.h>

#define B_    32
#define T_    128
#define IN_   256
#define H_    512
#define N_    128
#define R_    4
#define W_    64
#define RW_   256
#define FOUT_ 256
#define IF_   471
#define EPSF  1e-6f
#define KT_   256
#define KPAD  260
#define NBLK  144

// ---------- workspace layout (float offsets) ----------
#define OFF_H0   0
#define OFF_H1   (H_*B_)                 // 16384
#define OFF_C    (2*H_*B_)               // 32768
#define OFF_LR   (3*H_*B_)               // 49152
#define OFF_XI   (OFF_LR + RW_*B_)       // 57344 (480 rows padded)
#define OFF_MEM  (OFF_XI + 480*B_)       // 72704
#define OFF_LINK (OFF_MEM + B_*N_*W_)    // 334848
#define OFF_PREC (OFF_LINK + B_*N_*N_)   // 859136
#define OFF_RW   (OFF_PREC + B_*N_)      // 863232
#define OFF_WW   (OFF_RW + B_*R_*N_)     // 879616
#define OFF_USG  (OFF_WW + B_*N_)        // 883712
#define WS_STATE (OFF_USG + B_*N_)       // 887808 floats
// barrier counters (unsigned), separate cache lines
#define OFF_BAR  WS_STATE                // +0, +64, +128 (ints)
#define WS_TOTAL (WS_STATE + 192)

__device__ __forceinline__ float sig_(float x)   { return 1.0f / (1.0f + expf(-x)); }
__device__ __forceinline__ float splus_(float x) { return fmaxf(x, 0.0f) + log1pf(expf(-fabsf(x))); }

__device__ __forceinline__ unsigned long long shflx64(unsigned long long v, int m) {
    unsigned int lo = (unsigned int)v, hi = (unsigned int)(v >> 32);
    lo = (unsigned int)__shfl_xor((int)lo, m);
    hi = (unsigned int)__shfl_xor((int)hi, m);
    return ((unsigned long long)hi << 32) | lo;
}

__global__ void k_init(float* p, int n) {
    for (int i = blockIdx.x * blockDim.x + threadIdx.x; i < n; i += gridDim.x * blockDim.x)
        p[i] = 0.0f;
}

// ---------- grid barrier (monotonic counter, agent scope, release/acquire) ----------
__device__ __forceinline__ void gbar(unsigned* cnt, unsigned target) {
    __threadfence();                       // release: publish this thread's stores
    __syncthreads();
    if (threadIdx.x == 0) {
        __hip_atomic_fetch_add(cnt, 1u, __ATOMIC_ACQ_REL, __HIP_MEMORY_SCOPE_AGENT);
        while (__hip_atomic_load(cnt, __ATOMIC_ACQUIRE, __HIP_MEMORY_SCOPE_AGENT) < target)
            __builtin_amdgcn_s_sleep(2);
        __threadfence();                   // acquire: invalidate stale cache
    }
    __syncthreads();
}

// ---------- shared-memory overlays ----------
struct SA { float act[32 * KPAD]; float sg[4][4][32]; };
struct SM {
    float mem[N_ * (W_ + 1)];
    float rw[R_*N_], fwd[R_*N_], bwd[R_*N_], cr[R_*N_];
    float bpart[4][R_][N_];
    float cw[N_], usage[N_], alloc[N_], wwv[N_], prc[N_], minv[N_];
    float rkeys[R_*W_], wkey[W_], ev[W_], wv[W_];
    float rstr[R_], fg[R_], kinv[R_], m1[R_], modes[R_*3], sc[8];
    unsigned long long key[N_];
};

// ---- stage a [256][32] tile from [k][b]-major source into lds[b][k] ----
__device__ __forceinline__ void stage_kb(const float* __restrict__ src, float* lds, int tid) {
    #pragma unroll
    for (int i = 0; i < 8; ++i) {
        int f = i * 256 + tid;
        int k = f >> 3;
        int b4 = (f & 7) << 2;
        float4 v = reinterpret_cast<const float4*>(src)[f];
        lds[(b4 + 0) * KPAD + k] = v.x;
        lds[(b4 + 1) * KPAD + k] = v.y;
        lds[(b4 + 2) * KPAD + k] = v.z;
        lds[(b4 + 3) * KPAD + k] = v.w;
    }
}

__device__ __forceinline__ void stage_x(const float* __restrict__ x, int t, float* lds, int tid) {
    #pragma unroll
    for (int i = 0; i < 8; ++i) {
        int f = i * 256 + tid;
        int b  = f >> 6;
        int k4 = (f & 63) << 2;
        float4 v = *reinterpret_cast<const float4*>(x + ((size_t)b * T_ + t) * IN_ + k4);
        *reinterpret_cast<float4*>(&lds[b * KPAD + k4]) = v;
    }
}

__device__ __forceinline__ void tile_mac4(const float* lds,
        const float* __restrict__ w0p, const float* __restrict__ w1p,
        const float* __restrict__ w2p, const float* __restrict__ w3p,
        int lane, float* v)
{
    float4 w0 = *reinterpret_cast<const float4*>(w0p + lane * 4);
    float4 w1 = *reinterpret_cast<const float4*>(w1p + lane * 4);
    float4 w2 = *reinterpret_cast<const float4*>(w2p + lane * 4);
    float4 w3 = *reinterpret_cast<const float4*>(w3p + lane * 4);
    #pragma unroll
    for (int b = 0; b < 32; ++b) {
        float4 a = *reinterpret_cast<const float4*>(lds + b * KPAD + lane * 4);
        v[0*32+b] = fmaf(w0.w, a.w, fmaf(w0.z, a.z, fmaf(w0.y, a.y, fmaf(w0.x, a.x, v[0*32+b]))));
        v[1*32+b] = fmaf(w1.w, a.w, fmaf(w1.z, a.z, fmaf(w1.y, a.y, fmaf(w1.x, a.x, v[1*32+b]))));
        v[2*32+b] = fmaf(w2.w, a.w, fmaf(w2.z, a.z, fmaf(w2.y, a.y, fmaf(w2.x, a.x, v[2*32+b]))));
        v[3*32+b] = fmaf(w3.w, a.w, fmaf(w3.z, a.z, fmaf(w3.y, a.y, fmaf(w3.x, a.x, v[3*32+b]))));
    }
}

__device__ __forceinline__ void fold128(float* v, int lane) {
    #define FOLD_STAGE(D, HALF) { _Pragma("unroll") \
        for (int i = 0; i < HALF; ++i) { \
            float a_ = v[i], c_ = v[i + HALF]; \
            float t_ = (lane & D) ? a_ : c_; \
            t_ = __shfl_xor(t_, D); \
            v[i] = (lane & D) ? (c_ + t_) : (a_ + t_); } }
    FOLD_STAGE(32, 64) FOLD_STAGE(16, 32) FOLD_STAGE(8, 16)
    FOLD_STAGE(4, 8)   FOLD_STAGE(2, 4)   FOLD_STAGE(1, 2)
    #undef FOLD_STAGE
}

// ---------- phase bodies ----------
__device__ void gates_body(SA& sa, int bid, int tid,
        const float* __restrict__ x, const float* __restrict__ Wih,
        const float* __restrict__ Whh, const float* __restrict__ bih,
        const float* __restrict__ bhh,
        const float* __restrict__ hprev, float* __restrict__ hnew,
        float* __restrict__ c, const float* __restrict__ lr, int t)
{
    int lane = tid & 63, wid = tid >> 6;
    float v[128];
    #pragma unroll
    for (int i = 0; i < 128; ++i) v[i] = 0.0f;
    int j = bid * 4 + wid;
    for (int kt = 0; kt < 4; ++kt) {
        __syncthreads();
        if (kt == 0)      stage_x(x, t, sa.act, tid);
        else if (kt == 1) stage_kb(lr, sa.act, tid);
        else              stage_kb(hprev + (kt - 2) * KT_ * B_, sa.act, tid);
        __syncthreads();
        const float *w0, *w1, *w2, *w3;
        if (kt < 2) {
            w0 = Wih + ((size_t)(0*H_ + j)) * 512 + kt * 256;
            w1 = Wih + ((size_t)(1*H_ + j)) * 512 + kt * 256;
            w2 = Wih + ((size_t)(2*H_ + j)) * 512 + kt * 256;
            w3 = Wih + ((size_t)(3*H_ + j)) * 512 + kt * 256;
        } else {
            w0 = Whh + ((size_t)(0*H_ + j)) * 512 + (kt - 2) * 256;
            w1 = Whh + ((size_t)(1*H_ + j)) * 512 + (kt - 2) * 256;
            w2 = Whh + ((size_t)(2*H_ + j)) * 512 + (kt - 2) * 256;
            w3 = Whh + ((size_t)(3*H_ + j)) * 512 + (kt - 2) * 256;
        }
        tile_mac4(sa.act, w0, w1, w2, w3, lane, v);
    }
    fold128(v, lane);
    int r = (lane >> 4) & 3, b0 = (lane & 15) * 2;
    sa.sg[wid][r][b0]     = v[0];
    sa.sg[wid][r][b0 + 1] = v[1];
    __syncthreads();
    if (lane < 32) {
        int b = lane;
        float ai = sa.sg[wid][0][b] + bih[j]          + bhh[j];
        float af = sa.sg[wid][1][b] + bih[H_ + j]     + bhh[H_ + j];
        float ag = sa.sg[wid][2][b] + bih[2*H_ + j]   + bhh[2*H_ + j];
        float ao = sa.sg[wid][3][b] + bih[3*H_ + j]   + bhh[3*H_ + j];
        float ig = sig_(ai), fg = sig_(af), gg = tanhf(ag), og = sig_(ao);
        float cn = fg * c[j*B_ + b] + ig * gg;
        c[j*B_ + b] = cn;
        hnew[j*B_ + b] = og * tanhf(cn);
    }
}

__device__ void out_body(SA& sa, int bid, int tid,
        const float* __restrict__ Wemb, const float* __restrict__ bemb,
        const float* __restrict__ hsrc, const float* __restrict__ lr,
        float* __restrict__ out, int tcol)
{
    int lane = tid & 63, wid = tid >> 6;
    float v[128];
    #pragma unroll
    for (int i = 0; i < 128; ++i) v[i] = 0.0f;
    int rowbase = (bid - 128) * 16 + wid * 4;
    for (int kt = 0; kt < 3; ++kt) {
        __syncthreads();
        if (kt < 2) stage_kb(hsrc + kt * KT_ * B_, sa.act, tid);
        else        stage_kb(lr, sa.act, tid);
        __syncthreads();
        const float* w0 = Wemb + (size_t)(rowbase + 0) * 768 + kt * 256;
        const float* w1 = Wemb + (size_t)(rowbase + 1) * 768 + kt * 256;
        const float* w2 = Wemb + (size_t)(rowbase + 2) * 768 + kt * 256;
        const float* w3 = Wemb + (size_t)(rowbase + 3) * 768 + kt * 256;
        tile_mac4(sa.act, w0, w1, w2, w3, lane, v);
    }
    fold128(v, lane);
    int rloc = (lane >> 4) & 3, b0 = (lane & 15) * 2;
    int row = rowbase + rloc;
    float bb = bemb[row];
    out[((size_t)b0       * T_ + tcol) * FOUT_ + row] = v[0] + bb;
    out[((size_t)(b0 + 1) * T_ + tcol) * FOUT_ + row] = v[1] + bb;
}

__device__ void xi_body(SA& sa, int bid, int tid,
        const float* __restrict__ Wif, const float* __restrict__ bif,
        const float* __restrict__ h, float* __restrict__ xi)
{
    int lane = tid & 63, wid = tid >> 6;
    float v[128];
    #pragma unroll
    for (int i = 0; i < 128; ++i) v[i] = 0.0f;
    int rowbase = (bid - 32) * 16 + wid * 4;
    int r0 = min(rowbase + 0, IF_ - 1), r1 = min(rowbase + 1, IF_ - 1);
    int r2 = min(rowbase + 2, IF_ - 1), r3 = min(rowbase + 3, IF_ - 1);
    for (int kt = 0; kt < 2; ++kt) {
        __syncthreads();
        stage_kb(h + kt * KT_ * B_, sa.act, tid);
        __syncthreads();
        tile_mac4(sa.act, Wif + (size_t)r0 * 512 + kt * 256, Wif + (size_t)r1 * 512 + kt * 256,
                          Wif + (size_t)r2 * 512 + kt * 256, Wif + (size_t)r3 * 512 + kt * 256,
                  lane, v);
    }
    fold128(v, lane);
    int rloc = (lane >> 4) & 3, b0 = (lane & 15) * 2;
    int row = rowbase + rloc;
    if (row < IF_) {
        float bb = bif[row];
        xi[row * B_ + b0]     = v[0] + bb;
        xi[row * B_ + b0 + 1] = v[1] + bb;
    }
}

__device__ void mem_body(SM& sm, int b, int tid,
        const float* __restrict__ xi, float* __restrict__ gmem,
        float* __restrict__ glink, float* __restrict__ gprec,
        float* __restrict__ grw, float* __restrict__ gww,
        float* __restrict__ gusg, float* __restrict__ glr)
{
    const int lane = tid & 63, wid = tid >> 6;

    // 1. parse interface + load state
    for (int i = tid; i < IF_; i += 256) {
        float vv = xi[i*B_ + b];
        if      (i < 256) sm.rkeys[i]     = tanhf(vv);
        else if (i < 260) sm.rstr[i-256]  = splus_(vv);
        else if (i < 324) sm.wkey[i-260]  = tanhf(vv);
        else if (i < 325) sm.sc[0]        = splus_(vv);
        else if (i < 389) sm.ev[i-325]    = sig_(vv);
        else if (i < 453) sm.wv[i-389]    = tanhf(vv);
        else if (i < 457) sm.fg[i-453]    = sig_(vv);
        else if (i < 458) sm.sc[1]        = sig_(vv);
        else if (i < 459) sm.sc[2]        = sig_(vv);
        else              sm.modes[i-459] = vv;
    }
    for (int i = tid; i < R_*N_; i += 256) sm.rw[i] = grw[(size_t)b*R_*N_ + i];
    for (int i = tid; i < N_*W_; i += 256)
        sm.mem[(i >> 6) * (W_+1) + (i & 63)] = gmem[(size_t)b*N_*W_ + i];
    if (tid < N_) sm.prc[tid] = gprec[b*N_ + tid];
    __syncthreads();

    // 2. usage update, sort key, pre-update norms, head norms, modes softmax
    unsigned long long key = ~0ull;
    if (tid < N_) {
        float p = 1.0f;
        #pragma unroll
        for (int r = 0; r < R_; ++r) p *= 1.0f - sm.fg[r] * sm.rw[r*N_ + tid];
        float uo = gusg[b*N_ + tid], w0 = gww[b*N_ + tid];
        float u = (uo + w0 - uo*w0) * p;
        sm.usage[tid] = u;
        gusg[b*N_ + tid] = u;
        unsigned int fb = __float_as_uint(u);
        fb = (fb & 0x80000000u) ? ~fb : (fb | 0x80000000u);
        key = ((unsigned long long)fb << 32) | (unsigned int)tid;
        float s = 0.0f;
        for (int w = 0; w < W_; ++w) { float m = sm.mem[tid*(W_+1)+w]; s += m*m; }
        sm.minv[tid] = 1.0f / (sqrtf(s) + EPSF);
    }
    if (tid >= 128 && tid < 128 + R_) {
        int r = tid - 128;
        float s = 0.0f;
        for (int w = 0; w < W_; ++w) { float kv = sm.rkeys[r*W_+w]; s += kv*kv; }
        sm.kinv[r] = 1.0f / (sqrtf(s) + EPSF);
    }
    if (tid == 132) {
        float s = 0.0f;
        for (int w = 0; w < W_; ++w) s += sm.wkey[w]*sm.wkey[w];
        sm.sc[5] = 1.0f / (sqrtf(s) + EPSF);
    }
    if (tid >= 136 && tid < 136 + R_) {
        int r = tid - 136;
        float m0 = sm.modes[r*3], m1 = sm.modes[r*3+1], m2 = sm.modes[r*3+2];
        float mx = fmaxf(m0, fmaxf(m1, m2));
        float e0 = expf(m0-mx), e1 = expf(m1-mx), e2 = expf(m2-mx);
        float inv = 1.0f / (e0 + e1 + e2);
        sm.modes[r*3] = e0*inv; sm.modes[r*3+1] = e1*inv; sm.modes[r*3+2] = e2*inv;
    }
    __syncthreads();

    // 3. write-content dot, then register bitonic sort
    if (tid < N_) {
        float d = 0.0f;
        for (int w = 0; w < W_; ++w) d += sm.wkey[w] * sm.mem[tid*(W_+1)+w];
        sm.cw[tid] = d * sm.minv[tid] * sm.sc[5] * sm.sc[0];
    }
    for (int k = 2; k <= N_; k <<= 1) {
        for (int j = k >> 1; j > 0; j >>= 1) {
            unsigned long long pk;
            if (j == 64) {
                if (tid < N_) sm.key[tid] = key;
                __syncthreads();
                pk = (tid < N_) ? sm.key[tid ^ 64] : key;
                __syncthreads();
            } else {
                pk = shflx64(key, j);
            }
            bool lower = (tid & j) == 0;
            bool asc   = (tid & k) == 0;
            if ((key > pk) == (lower == asc)) key = pk;
        }
    }

    // 4. allocation via shfl product-scan; wave2 does write softmax
    float su = 0.0f, ex = 1.0f; int sidx = 0;
    if (tid < N_) {
        sidx = (int)(key & 0xffffffffu);
        su = sm.usage[sidx];
        float p = su;
        #pragma unroll
        for (int off = 1; off < 64; off <<= 1) {
            float pv = __shfl_up(p, off);
            if (lane >= off) p *= pv;
        }
        if (tid == 63) sm.sc[7] = p;
        float e = __shfl_up(p, 1);
        ex = (lane == 0) ? 1.0f : e;
    }
    __syncthreads();
    if (tid < N_) {
        if (tid >= 64) ex *= sm.sc[7];
        sm.alloc[sidx] = (1.0f - su) * ex;
    }
    if (wid == 2) {
        float v0 = sm.cw[lane], v1 = sm.cw[lane+64];
        float m = fmaxf(v0, v1);
        #pragma unroll
        for (int o = 32; o >= 1; o >>= 1) m = fmaxf(m, __shfl_xor(m, o));
        float e0 = expf(v0 - m), e1 = expf(v1 - m);
        float s = e0 + e1;
        #pragma unroll
        for (int o = 32; o >= 1; o >>= 1) s += __shfl_xor(s, o);
        sm.cw[lane] = e0; sm.cw[lane+64] = e1;
        if (lane == 0) sm.sc[4] = 1.0f / s;
    }
    __syncthreads();

    // 5. write weighting
    if (tid < N_) {
        float cwn = sm.cw[tid] * sm.sc[4];
        float w = sm.sc[2] * (sm.sc[1] * sm.alloc[tid] + (1.0f - sm.sc[1]) * cwn);
        sm.wwv[tid] = w;
        gww[b*N_ + tid] = w;
    }
    __syncthreads();

    // 6. memory update + sum_ww (wave3)
    for (int i = tid; i < N_*W_; i += 256) {
        int n = i >> 6, w = i & 63;
        float m = sm.mem[n*(W_+1)+w];
        m = m * (1.0f - sm.wwv[n]*sm.ev[w]) + sm.wwv[n]*sm.wv[w];
        sm.mem[n*(W_+1)+w] = m;
        gmem[(size_t)b*N_*W_ + i] = m;
    }
    if (wid == 3) {
        float s = sm.wwv[lane] + sm.wwv[lane+64];
        #pragma unroll
        for (int o = 32; o >= 1; o >>= 1) s += __shfl_xor(s, o);
        if (lane == 0) sm.sc[6] = s;
    }
    __syncthreads();

    // 7. fused link update + fwd reduce + bwd partials (R1-proven, single pass)
    {
        float bl0[R_], bl1[R_];
        #pragma unroll
        for (int r = 0; r < R_; ++r) { bl0[r] = 0.0f; bl1[r] = 0.0f; }
        size_t base = (size_t)b * N_ * N_;
        for (int row = wid*32; row < wid*32 + 32; ++row) {
            float wwr = sm.wwv[row];
            float l0 = glink[base + row*N_ + lane];
            float l1 = glink[base + row*N_ + 64 + lane];
            float n0 = (1.0f - wwr - sm.wwv[lane])      * l0 + wwr * sm.prc[lane];
            float n1 = (1.0f - wwr - sm.wwv[64 + lane]) * l1 + wwr * sm.prc[64 + lane];
            if (row == lane)      n0 = 0.0f;
            if (row == 64 + lane) n1 = 0.0f;
            glink[base + row*N_ + lane]      = n0;
            glink[base + row*N_ + 64 + lane] = n1;
            #pragma unroll
            for (int r = 0; r < R_; ++r) {
                float vv = n0 * sm.rw[r*N_ + lane] + n1 * sm.rw[r*N_ + 64 + lane];
                vv += __shfl_xor(vv, 32); vv += __shfl_xor(vv, 16); vv += __shfl_xor(vv, 8);
                vv += __shfl_xor(vv, 4);  vv += __shfl_xor(vv, 2);  vv += __shfl_xor(vv, 1);
                if (lane == 0) sm.fwd[r*N_ + row] = vv;
                bl0[r] += n0 * sm.rw[r*N_ + row];
                bl1[r] += n1 * sm.rw[r*N_ + row];
            }
        }
        #pragma unroll
        for (int r = 0; r < R_; ++r) {
            sm.bpart[wid][r][lane]      = bl0[r];
            sm.bpart[wid][r][64 + lane] = bl1[r];
        }
    }
    __syncthreads();

    // 8. bwd combine + precedence + post-update norms
    if (tid < N_) {
        #pragma unroll
        for (int r = 0; r < R_; ++r)
            sm.bwd[r*N_ + tid] = sm.bpart[0][r][tid] + sm.bpart[1][r][tid]
                               + sm.bpart[2][r][tid] + sm.bpart[3][r][tid];
        float p = (1.0f - sm.sc[6]) * sm.prc[tid] + sm.wwv[tid];
        gprec[b*N_ + tid] = p;
        float s = 0.0f;
        for (int w = 0; w < W_; ++w) { float m = sm.mem[tid*(W_+1)+w]; s += m*m; }
        sm.minv[tid] = 1.0f / (sqrtf(s) + EPSF);
    }
    __syncthreads();

    // 9. read-content dots (post-update mem)
    for (int i = tid; i < R_*N_; i += 256) {
        int r = i >> 7, n = i & 127;
        float d = 0.0f;
        for (int w = 0; w < W_; ++w) d += sm.rkeys[r*W_+w] * sm.mem[n*(W_+1)+w];
        sm.cr[i] = d * sm.minv[n] * sm.kinv[r] * sm.rstr[r];
    }
    __syncthreads();

    // 10. per-head softmax (wave = head)
    {
        int r = wid;
        float v0 = sm.cr[r*N_ + lane], v1 = sm.cr[r*N_ + lane + 64];
        float m = fmaxf(v0, v1);
        #pragma unroll
        for (int o = 32; o >= 1; o >>= 1) m = fmaxf(m, __shfl_xor(m, o));
        float e0 = expf(v0 - m), e1 = expf(v1 - m);
        float s = e0 + e1;
        #pragma unroll
        for (int o = 32; o >= 1; o >>= 1) s += __shfl_xor(s, o);
        sm.cr[r*N_ + lane] = e0; sm.cr[r*N_ + lane + 64] = e1;
        if (lane == 0) sm.m1[r] = sm.modes[r*3+1] / s;
    }
    __syncthreads();

    // 11. new read weights
    for (int i = tid; i < R_*N_; i += 256) {
        int r = i >> 7;
        float vv = sm.modes[r*3] * sm.bwd[i] + sm.m1[r] * sm.cr[i] + sm.modes[r*3+2] * sm.fwd[i];
        sm.cr[i] = vv;
        grw[(size_t)b*R_*N_ + i] = vv;
    }
    __syncthreads();

    // 12. read vectors -> last_read ([k][b])
    for (int i = tid; i < R_*W_; i += 256) {
        int r = i >> 6, w = i & 63;
        float d = 0.0f;
        for (int n = 0; n < N_; ++n) d += sm.cr[r*N_ + n] * sm.mem[n*(W_+1)+w];
        glr[i*B_ + b] = d;
    }
}

// ---------- the persistent kernel (plain launch; 144 blocks <= 256 CUs) ----------
__global__ __launch_bounds__(256, 1) void k_fused(
        const float* __restrict__ x, const float* __restrict__ Wih,
        const float* __restrict__ Whh, const float* __restrict__ bih,
        const float* __restrict__ bhh, const float* __restrict__ Wif,
        const float* __restrict__ bif, const float* __restrict__ Wemb,
        const float* __restrict__ bemb, float* __restrict__ out,
        float* __restrict__ ws)
{
    __shared__ __align__(16) char smem_raw[(sizeof(SM) > sizeof(SA)) ? sizeof(SM) : sizeof(SA)];
    SA& sa = *reinterpret_cast<SA*>(smem_raw);
    SM& sm = *reinterpret_cast<SM*>(smem_raw);

    const int bid = blockIdx.x, tid = threadIdx.x;

    float* h0   = ws + OFF_H0;
    float* h1   = ws + OFF_H1;
    float* c    = ws + OFF_C;
    float* lr   = ws + OFF_LR;
    float* xi   = ws + OFF_XI;
    float* gmem = ws + OFF_MEM;
    float* glink= ws + OFF_LINK;
    float* gprec= ws + OFF_PREC;
    float* grw  = ws + OFF_RW;
    float* gww  = ws + OFF_WW;
    float* gusg = ws + OFF_USG;
    unsigned* cnt = (unsigned*)(ws + OFF_BAR);

    for (int t = 0; t < T_; ++t) {
        const float* hp = (t & 1) ? h1 : h0;
        float*       hn = (t & 1) ? h0 : h1;

        // phase A: gates (blocks 0..127), out(t-1) (blocks 128..143)
        if (bid < 128)
            gates_body(sa, bid, tid, x, Wih, Whh, bih, bhh, hp, hn, c, lr, t);
        else if (t > 0)
            out_body(sa, bid, tid, Wemb, bemb, hp, lr, out, t - 1);
        gbar(cnt + 0, (unsigned)(NBLK * (t + 1)));

        // phase B: xi (blocks 32..61)
        if (bid >= 32 && bid < 62)
            xi_body(sa, bid, tid, Wif, bif, hn, xi);
        if (bid < 62)
            gbar(cnt + 64, (unsigned)(62 * (t + 1)));

        // phase C: memory machine (blocks 0..31)
        if (bid < 32)
            mem_body(sm, bid, tid, xi, gmem, glink, gprec, grw, gww, gusg, lr);
        gbar(cnt + 128, (unsigned)(NBLK * (t + 1)));
    }

    // tail: final out(T-1)
    if (bid >= 128) {
        const float* hfin = ((T_ - 1) & 1) ? h0 : h1;
        out_body(sa, bid, tid, Wemb, bemb, hfin, lr, out, T_ - 1);
    }
}

extern "C" void kernel_launch(void* const* d_in, const int* in_sizes, int n_in,
                              void* d_out, int out_size, void* d_ws, size_t ws_size,
                              hipStream_t stream)
{
    const float* x    = (const float*)d_in[0];
    const float* Wih  = (const float*)d_in[1];
    const float* Whh  = (const float*)d_in[2];
    const float* bih  = (const float*)d_in[3];
    const float* bhh  = (const float*)d_in[4];
    const float* Wif  = (const float*)d_in[5];
    const float* bif  = (const float*)d_in[6];
    const float* Wemb = (const float*)d_in[7];
    const float* bemb = (const float*)d_in[8];
    float* out = (float*)d_out;
    float* ws  = (float*)d_ws;

    k_init<<<512, 256, 0, stream>>>(ws, WS_TOTAL);

    k_fused<<<dim3(NBLK), dim3(256), 0, stream>>>(x, Wih, Whh, bih, bhh,
                                                  Wif, bif, Wemb, bemb, out, ws);
}

// Round 6
// 12238.849 us; speedup vs baseline: 1.7154x; 1.7154x over previous
//
#include <hip/hip_runtime.h>
#include <math.h>

#define B_    32
#define T_    128
#define IN_   256
#define H_    512
#define N_    128
#define R_    4
#define W_    64
#define RW_   256
#define FOUT_ 256
#define IF_   471
#define EPSF  1e-6f
#define KT_   256
#define KPAD  260
#define NBLK  144

// ---------- workspace layout (float offsets) ----------
#define OFF_H0   0
#define OFF_H1   (H_*B_)                 // 16384
#define OFF_C    (2*H_*B_)               // 32768
#define OFF_LR   (3*H_*B_)               // 49152
#define OFF_MEM  (OFF_LR + RW_*B_)       // 57344
#define OFF_LINK (OFF_MEM + B_*N_*W_)
#define OFF_PREC (OFF_LINK + B_*N_*N_)
#define OFF_RW   (OFF_PREC + B_*N_)
#define OFF_WW   (OFF_RW + B_*R_*N_)
#define OFF_USG  (OFF_WW + B_*N_)
#define WS_STATE (OFF_USG + B_*N_)
// flag arrays: one slot per block, 128B apart (32 uints), no sharing
#define OFF_FLAGA WS_STATE               // 144*32 uints
#define OFF_FLAGC (OFF_FLAGA + NBLK*32)  // 32*32 uints
#define WS_TOTAL  (OFF_FLAGC + 32*32)

__device__ __forceinline__ float sig_(float x)   { return 1.0f / (1.0f + expf(-x)); }
__device__ __forceinline__ float splus_(float x) { return fmaxf(x, 0.0f) + log1pf(expf(-fabsf(x))); }

__device__ __forceinline__ unsigned long long shflx64(unsigned long long v, int m) {
    unsigned int lo = (unsigned int)v, hi = (unsigned int)(v >> 32);
    lo = (unsigned int)__shfl_xor((int)lo, m);
    hi = (unsigned int)__shfl_xor((int)hi, m);
    return ((unsigned long long)hi << 32) | lo;
}

__global__ void k_init(float* p, int n) {
    for (int i = blockIdx.x * blockDim.x + threadIdx.x; i < n; i += gridDim.x * blockDim.x)
        p[i] = 0.0f;
}

// ---------- flag-based grid sync (no RMW, one fence per block per barrier) ----------
// post: all block stores done -> single release fence (thread 0) -> relaxed store
__device__ __forceinline__ void post_flag(unsigned* slot, unsigned val) {
    __syncthreads();
    if (threadIdx.x == 0) {
        __threadfence();   // release: writeback this XCD's dirty L2 lines
        __hip_atomic_store(slot, val, __ATOMIC_RELAXED, __HIP_MEMORY_SCOPE_AGENT);
    }
}
// wait: thread i polls flag i (relaxed, no cache-invalidate storm);
// ONE acquire fence per block after all flags observed.
__device__ __forceinline__ void wait_flags(const unsigned* flags, int nf, unsigned val) {
    if ((int)threadIdx.x < nf) {
        while (__hip_atomic_load(&flags[threadIdx.x * 32], __ATOMIC_RELAXED,
                                 __HIP_MEMORY_SCOPE_AGENT) < val)
            __builtin_amdgcn_s_sleep(4);
    }
    __syncthreads();
    if (threadIdx.x == 0) __threadfence();  // acquire: invalidate stale L1/L2
    __syncthreads();
}

// ---------- shared-memory overlays ----------
struct SA { float act[32 * KPAD]; float sg[4][4][32]; };
struct SM {
    float mem[N_ * (W_ + 1)];
    float hb[H_];
    float rw[R_*N_], fwd[R_*N_], bwd[R_*N_], cr[R_*N_];
    float bpart[4][R_][N_];
    float cw[N_], usage[N_], alloc[N_], wwv[N_], prc[N_], minv[N_];
    float rkeys[R_*W_], wkey[W_], ev[W_], wv[W_];
    float rstr[R_], fg[R_], kinv[R_], m1[R_], modes[R_*3], sc[8];
    unsigned long long key[N_];
};

// ---- stage a [256][32] tile from [k][b]-major source into lds[b][k] ----
__device__ __forceinline__ void stage_kb(const float* __restrict__ src, float* lds, int tid) {
    #pragma unroll
    for (int i = 0; i < 8; ++i) {
        int f = i * 256 + tid;
        int k = f >> 3;
        int b4 = (f & 7) << 2;
        float4 v = reinterpret_cast<const float4*>(src)[f];
        lds[(b4 + 0) * KPAD + k] = v.x;
        lds[(b4 + 1) * KPAD + k] = v.y;
        lds[(b4 + 2) * KPAD + k] = v.z;
        lds[(b4 + 3) * KPAD + k] = v.w;
    }
}

__device__ __forceinline__ void stage_x(const float* __restrict__ x, int t, float* lds, int tid) {
    #pragma unroll
    for (int i = 0; i < 8; ++i) {
        int f = i * 256 + tid;
        int b  = f >> 6;
        int k4 = (f & 63) << 2;
        float4 v = *reinterpret_cast<const float4*>(x + ((size_t)b * T_ + t) * IN_ + k4);
        *reinterpret_cast<float4*>(&lds[b * KPAD + k4]) = v;
    }
}

__device__ __forceinline__ void tile_mac4(const float* lds,
        const float* __restrict__ w0p, const float* __restrict__ w1p,
        const float* __restrict__ w2p, const float* __restrict__ w3p,
        int lane, float* v)
{
    float4 w0 = *reinterpret_cast<const float4*>(w0p + lane * 4);
    float4 w1 = *reinterpret_cast<const float4*>(w1p + lane * 4);
    float4 w2 = *reinterpret_cast<const float4*>(w2p + lane * 4);
    float4 w3 = *reinterpret_cast<const float4*>(w3p + lane * 4);
    #pragma unroll
    for (int b = 0; b < 32; ++b) {
        float4 a = *reinterpret_cast<const float4*>(lds + b * KPAD + lane * 4);
        v[0*32+b] = fmaf(w0.w, a.w, fmaf(w0.z, a.z, fmaf(w0.y, a.y, fmaf(w0.x, a.x, v[0*32+b]))));
        v[1*32+b] = fmaf(w1.w, a.w, fmaf(w1.z, a.z, fmaf(w1.y, a.y, fmaf(w1.x, a.x, v[1*32+b]))));
        v[2*32+b] = fmaf(w2.w, a.w, fmaf(w2.z, a.z, fmaf(w2.y, a.y, fmaf(w2.x, a.x, v[2*32+b]))));
        v[3*32+b] = fmaf(w3.w, a.w, fmaf(w3.z, a.z, fmaf(w3.y, a.y, fmaf(w3.x, a.x, v[3*32+b]))));
    }
}

__device__ __forceinline__ void fold128(float* v, int lane) {
    #define FOLD_STAGE(D, HALF) { _Pragma("unroll") \
        for (int i = 0; i < HALF; ++i) { \
            float a_ = v[i], c_ = v[i + HALF]; \
            float t_ = (lane & D) ? a_ : c_; \
            t_ = __shfl_xor(t_, D); \
            v[i] = (lane & D) ? (c_ + t_) : (a_ + t_); } }
    FOLD_STAGE(32, 64) FOLD_STAGE(16, 32) FOLD_STAGE(8, 16)
    FOLD_STAGE(4, 8)   FOLD_STAGE(2, 4)   FOLD_STAGE(1, 2)
    #undef FOLD_STAGE
}

// ---------- phase bodies ----------
__device__ void gates_body(SA& sa, int bid, int tid,
        const float* __restrict__ x, const float* __restrict__ Wih,
        const float* __restrict__ Whh, const float* __restrict__ bih,
        const float* __restrict__ bhh,
        const float* __restrict__ hprev, float* __restrict__ hnew,
        float* __restrict__ c, const float* __restrict__ lr, int t)
{
    int lane = tid & 63, wid = tid >> 6;
    float v[128];
    #pragma unroll
    for (int i = 0; i < 128; ++i) v[i] = 0.0f;
    int j = bid * 4 + wid;
    for (int kt = 0; kt < 4; ++kt) {
        __syncthreads();
        if (kt == 0)      stage_x(x, t, sa.act, tid);
        else if (kt == 1) stage_kb(lr, sa.act, tid);
        else              stage_kb(hprev + (kt - 2) * KT_ * B_, sa.act, tid);
        __syncthreads();
        const float *w0, *w1, *w2, *w3;
        if (kt < 2) {
            w0 = Wih + ((size_t)(0*H_ + j)) * 512 + kt * 256;
            w1 = Wih + ((size_t)(1*H_ + j)) * 512 + kt * 256;
            w2 = Wih + ((size_t)(2*H_ + j)) * 512 + kt * 256;
            w3 = Wih + ((size_t)(3*H_ + j)) * 512 + kt * 256;
        } else {
            w0 = Whh + ((size_t)(0*H_ + j)) * 512 + (kt - 2) * 256;
            w1 = Whh + ((size_t)(1*H_ + j)) * 512 + (kt - 2) * 256;
            w2 = Whh + ((size_t)(2*H_ + j)) * 512 + (kt - 2) * 256;
            w3 = Whh + ((size_t)(3*H_ + j)) * 512 + (kt - 2) * 256;
        }
        tile_mac4(sa.act, w0, w1, w2, w3, lane, v);
    }
    fold128(v, lane);
    int r = (lane >> 4) & 3, b0 = (lane & 15) * 2;
    sa.sg[wid][r][b0]     = v[0];
    sa.sg[wid][r][b0 + 1] = v[1];
    __syncthreads();
    if (lane < 32) {
        int b = lane;
        float ai = sa.sg[wid][0][b] + bih[j]          + bhh[j];
        float af = sa.sg[wid][1][b] + bih[H_ + j]     + bhh[H_ + j];
        float ag = sa.sg[wid][2][b] + bih[2*H_ + j]   + bhh[2*H_ + j];
        float ao = sa.sg[wid][3][b] + bih[3*H_ + j]   + bhh[3*H_ + j];
        float ig = sig_(ai), fg = sig_(af), gg = tanhf(ag), og = sig_(ao);
        float cn = fg * c[j*B_ + b] + ig * gg;
        c[j*B_ + b] = cn;
        hnew[j*B_ + b] = og * tanhf(cn);
    }
}

__device__ void out_body(SA& sa, int bid, int tid,
        const float* __restrict__ Wemb, const float* __restrict__ bemb,
        const float* __restrict__ hsrc, const float* __restrict__ lr,
        float* __restrict__ out, int tcol)
{
    int lane = tid & 63, wid = tid >> 6;
    float v[128];
    #pragma unroll
    for (int i = 0; i < 128; ++i) v[i] = 0.0f;
    int rowbase = (bid - 128) * 16 + wid * 4;
    for (int kt = 0; kt < 3; ++kt) {
        __syncthreads();
        if (kt < 2) stage_kb(hsrc + kt * KT_ * B_, sa.act, tid);
        else        stage_kb(lr, sa.act, tid);
        __syncthreads();
        const float* w0 = Wemb + (size_t)(rowbase + 0) * 768 + kt * 256;
        const float* w1 = Wemb + (size_t)(rowbase + 1) * 768 + kt * 256;
        const float* w2 = Wemb + (size_t)(rowbase + 2) * 768 + kt * 256;
        const float* w3 = Wemb + (size_t)(rowbase + 3) * 768 + kt * 256;
        tile_mac4(sa.act, w0, w1, w2, w3, lane, v);
    }
    fold128(v, lane);
    int rloc = (lane >> 4) & 3, b0 = (lane & 15) * 2;
    int row = rowbase + rloc;
    float bb = bemb[row];
    out[((size_t)b0       * T_ + tcol) * FOUT_ + row] = v[0] + bb;
    out[((size_t)(b0 + 1) * T_ + tcol) * FOUT_ + row] = v[1] + bb;
}

// memory machine for batch b; computes its own xi column (W_if GEMV vs LDS h)
__device__ void mem_body(SM& sm, int b, int tid,
        const float* __restrict__ Wif, const float* __restrict__ bif,
        const float* __restrict__ gh,   // h(t), [k][b]
        float* __restrict__ gmem, float* __restrict__ glink, float* __restrict__ gprec,
        float* __restrict__ grw, float* __restrict__ gww,
        float* __restrict__ gusg, float* __restrict__ glr)
{
    const int lane = tid & 63, wid = tid >> 6;

    // 0. stage h column + state
    for (int k = tid; k < H_; k += 256) sm.hb[k] = gh[k*B_ + b];
    for (int i = tid; i < R_*N_; i += 256) sm.rw[i] = grw[(size_t)b*R_*N_ + i];
    for (int i = tid; i < N_*W_; i += 256)
        sm.mem[(i >> 6) * (W_+1) + (i & 63)] = gmem[(size_t)b*N_*W_ + i];
    if (tid < N_) sm.prc[tid] = gprec[b*N_ + tid];
    __syncthreads();

    // 1. xi GEMV (2 rows/thread, 4 independent FMA chains each) + parse
    #pragma unroll
    for (int s = 0; s < 2; ++s) {
        int i = tid + s * 256;
        if (i < IF_) {
            const float4* wr = reinterpret_cast<const float4*>(Wif + (size_t)i * H_);
            float a0 = 0.f, a1 = 0.f, a2 = 0.f, a3 = 0.f;
            #pragma unroll 8
            for (int q = 0; q < H_/4; ++q) {
                float4 w4 = wr[q];
                a0 = fmaf(w4.x, sm.hb[q*4+0], a0);
                a1 = fmaf(w4.y, sm.hb[q*4+1], a1);
                a2 = fmaf(w4.z, sm.hb[q*4+2], a2);
                a3 = fmaf(w4.w, sm.hb[q*4+3], a3);
            }
            float vv = (a0 + a1) + (a2 + a3) + bif[i];
            if      (i < 256) sm.rkeys[i]     = tanhf(vv);
            else if (i < 260) sm.rstr[i-256]  = splus_(vv);
            else if (i < 324) sm.wkey[i-260]  = tanhf(vv);
            else if (i < 325) sm.sc[0]        = splus_(vv);
            else if (i < 389) sm.ev[i-325]    = sig_(vv);
            else if (i < 453) sm.wv[i-389]    = tanhf(vv);
            else if (i < 457) sm.fg[i-453]    = sig_(vv);
            else if (i < 458) sm.sc[1]        = sig_(vv);
            else if (i < 459) sm.sc[2]        = sig_(vv);
            else              sm.modes[i-459] = vv;
        }
    }
    __syncthreads();

    // 2. usage update, sort key, pre-update norms, head norms, modes softmax
    unsigned long long key = ~0ull;
    if (tid < N_) {
        float p = 1.0f;
        #pragma unroll
        for (int r = 0; r < R_; ++r) p *= 1.0f - sm.fg[r] * sm.rw[r*N_ + tid];
        float uo = gusg[b*N_ + tid], w0 = gww[b*N_ + tid];
        float u = (uo + w0 - uo*w0) * p;
        sm.usage[tid] = u;
        gusg[b*N_ + tid] = u;
        unsigned int fb = __float_as_uint(u);
        fb = (fb & 0x80000000u) ? ~fb : (fb | 0x80000000u);
        key = ((unsigned long long)fb << 32) | (unsigned int)tid;
        float s = 0.0f;
        for (int w = 0; w < W_; ++w) { float m = sm.mem[tid*(W_+1)+w]; s += m*m; }
        sm.minv[tid] = 1.0f / (sqrtf(s) + EPSF);
    }
    if (tid >= 128 && tid < 128 + R_) {
        int r = tid - 128;
        float s = 0.0f;
        for (int w = 0; w < W_; ++w) { float kv = sm.rkeys[r*W_+w]; s += kv*kv; }
        sm.kinv[r] = 1.0f / (sqrtf(s) + EPSF);
    }
    if (tid == 132) {
        float s = 0.0f;
        for (int w = 0; w < W_; ++w) s += sm.wkey[w]*sm.wkey[w];
        sm.sc[5] = 1.0f / (sqrtf(s) + EPSF);
    }
    if (tid >= 136 && tid < 136 + R_) {
        int r = tid - 136;
        float m0 = sm.modes[r*3], m1 = sm.modes[r*3+1], m2 = sm.modes[r*3+2];
        float mx = fmaxf(m0, fmaxf(m1, m2));
        float e0 = expf(m0-mx), e1 = expf(m1-mx), e2 = expf(m2-mx);
        float inv = 1.0f / (e0 + e1 + e2);
        sm.modes[r*3] = e0*inv; sm.modes[r*3+1] = e1*inv; sm.modes[r*3+2] = e2*inv;
    }
    __syncthreads();

    // 3. write-content dot, then register bitonic sort
    if (tid < N_) {
        float d = 0.0f;
        for (int w = 0; w < W_; ++w) d += sm.wkey[w] * sm.mem[tid*(W_+1)+w];
        sm.cw[tid] = d * sm.minv[tid] * sm.sc[5] * sm.sc[0];
    }
    for (int k = 2; k <= N_; k <<= 1) {
        for (int j = k >> 1; j > 0; j >>= 1) {
            unsigned long long pk;
            if (j == 64) {
                if (tid < N_) sm.key[tid] = key;
                __syncthreads();
                pk = (tid < N_) ? sm.key[tid ^ 64] : key;
                __syncthreads();
            } else {
                pk = shflx64(key, j);
            }
            bool lower = (tid & j) == 0;
            bool asc   = (tid & k) == 0;
            if ((key > pk) == (lower == asc)) key = pk;
        }
    }

    // 4. allocation via shfl product-scan; wave2 does write softmax
    float su = 0.0f, ex = 1.0f; int sidx = 0;
    if (tid < N_) {
        sidx = (int)(key & 0xffffffffu);
        su = sm.usage[sidx];
        float p = su;
        #pragma unroll
        for (int off = 1; off < 64; off <<= 1) {
            float pv = __shfl_up(p, off);
            if (lane >= off) p *= pv;
        }
        if (tid == 63) sm.sc[7] = p;
        float e = __shfl_up(p, 1);
        ex = (lane == 0) ? 1.0f : e;
    }
    __syncthreads();
    if (tid < N_) {
        if (tid >= 64) ex *= sm.sc[7];
        sm.alloc[sidx] = (1.0f - su) * ex;
    }
    if (wid == 2) {
        float v0 = sm.cw[lane], v1 = sm.cw[lane+64];
        float m = fmaxf(v0, v1);
        #pragma unroll
        for (int o = 32; o >= 1; o >>= 1) m = fmaxf(m, __shfl_xor(m, o));
        float e0 = expf(v0 - m), e1 = expf(v1 - m);
        float s = e0 + e1;
        #pragma unroll
        for (int o = 32; o >= 1; o >>= 1) s += __shfl_xor(s, o);
        sm.cw[lane] = e0; sm.cw[lane+64] = e1;
        if (lane == 0) sm.sc[4] = 1.0f / s;
    }
    __syncthreads();

    // 5. write weighting
    if (tid < N_) {
        float cwn = sm.cw[tid] * sm.sc[4];
        float w = sm.sc[2] * (sm.sc[1] * sm.alloc[tid] + (1.0f - sm.sc[1]) * cwn);
        sm.wwv[tid] = w;
        gww[b*N_ + tid] = w;
    }
    __syncthreads();

    // 6. memory update + sum_ww (wave3)
    for (int i = tid; i < N_*W_; i += 256) {
        int n = i >> 6, w = i & 63;
        float m = sm.mem[n*(W_+1)+w];
        m = m * (1.0f - sm.wwv[n]*sm.ev[w]) + sm.wwv[n]*sm.wv[w];
        sm.mem[n*(W_+1)+w] = m;
        gmem[(size_t)b*N_*W_ + i] = m;
    }
    if (wid == 3) {
        float s = sm.wwv[lane] + sm.wwv[lane+64];
        #pragma unroll
        for (int o = 32; o >= 1; o >>= 1) s += __shfl_xor(s, o);
        if (lane == 0) sm.sc[6] = s;
    }
    __syncthreads();

    // 7. fused link update + fwd reduce + bwd partials (single pass over link)
    {
        float bl0[R_], bl1[R_];
        #pragma unroll
        for (int r = 0; r < R_; ++r) { bl0[r] = 0.0f; bl1[r] = 0.0f; }
        size_t base = (size_t)b * N_ * N_;
        for (int row = wid*32; row < wid*32 + 32; ++row) {
            float wwr = sm.wwv[row];
            float l0 = glink[base + row*N_ + lane];
            float l1 = glink[base + row*N_ + 64 + lane];
            float n0 = (1.0f - wwr - sm.wwv[lane])      * l0 + wwr * sm.prc[lane];
            float n1 = (1.0f - wwr - sm.wwv[64 + lane]) * l1 + wwr * sm.prc[64 + lane];
            if (row == lane)      n0 = 0.0f;
            if (row == 64 + lane) n1 = 0.0f;
            glink[base + row*N_ + lane]      = n0;
            glink[base + row*N_ + 64 + lane] = n1;
            #pragma unroll
            for (int r = 0; r < R_; ++r) {
                float vv = n0 * sm.rw[r*N_ + lane] + n1 * sm.rw[r*N_ + 64 + lane];
                vv += __shfl_xor(vv, 32); vv += __shfl_xor(vv, 16); vv += __shfl_xor(vv, 8);
                vv += __shfl_xor(vv, 4);  vv += __shfl_xor(vv, 2);  vv += __shfl_xor(vv, 1);
                if (lane == 0) sm.fwd[r*N_ + row] = vv;
                bl0[r] += n0 * sm.rw[r*N_ + row];
                bl1[r] += n1 * sm.rw[r*N_ + row];
            }
        }
        #pragma unroll
        for (int r = 0; r < R_; ++r) {
            sm.bpart[wid][r][lane]      = bl0[r];
            sm.bpart[wid][r][64 + lane] = bl1[r];
        }
    }
    __syncthreads();

    // 8. bwd combine + precedence + post-update norms
    if (tid < N_) {
        #pragma unroll
        for (int r = 0; r < R_; ++r)
            sm.bwd[r*N_ + tid] = sm.bpart[0][r][tid] + sm.bpart[1][r][tid]
                               + sm.bpart[2][r][tid] + sm.bpart[3][r][tid];
        float p = (1.0f - sm.sc[6]) * sm.prc[tid] + sm.wwv[tid];
        gprec[b*N_ + tid] = p;
        float s = 0.0f;
        for (int w = 0; w < W_; ++w) { float m = sm.mem[tid*(W_+1)+w]; s += m*m; }
        sm.minv[tid] = 1.0f / (sqrtf(s) + EPSF);
    }
    __syncthreads();

    // 9. read-content dots (post-update mem)
    for (int i = tid; i < R_*N_; i += 256) {
        int r = i >> 7, n = i & 127;
        float d = 0.0f;
        for (int w = 0; w < W_; ++w) d += sm.rkeys[r*W_+w] * sm.mem[n*(W_+1)+w];
        sm.cr[i] = d * sm.minv[n] * sm.kinv[r] * sm.rstr[r];
    }
    __syncthreads();

    // 10. per-head softmax (wave = head)
    {
        int r = wid;
        float v0 = sm.cr[r*N_ + lane], v1 = sm.cr[r*N_ + lane + 64];
        float m = fmaxf(v0, v1);
        #pragma unroll
        for (int o = 32; o >= 1; o >>= 1) m = fmaxf(m, __shfl_xor(m, o));
        float e0 = expf(v0 - m), e1 = expf(v1 - m);
        float s = e0 + e1;
        #pragma unroll
        for (int o = 32; o >= 1; o >>= 1) s += __shfl_xor(s, o);
        sm.cr[r*N_ + lane] = e0; sm.cr[r*N_ + lane + 64] = e1;
        if (lane == 0) sm.m1[r] = sm.modes[r*3+1] / s;
    }
    __syncthreads();

    // 11. new read weights
    for (int i = tid; i < R_*N_; i += 256) {
        int r = i >> 7;
        float vv = sm.modes[r*3] * sm.bwd[i] + sm.m1[r] * sm.cr[i] + sm.modes[r*3+2] * sm.fwd[i];
        sm.cr[i] = vv;
        grw[(size_t)b*R_*N_ + i] = vv;
    }
    __syncthreads();

    // 12. read vectors -> last_read ([k][b])
    for (int i = tid; i < R_*W_; i += 256) {
        int r = i >> 6, w = i & 63;
        float d = 0.0f;
        for (int n = 0; n < N_; ++n) d += sm.cr[r*N_ + n] * sm.mem[n*(W_+1)+w];
        glr[i*B_ + b] = d;
    }
}

// ---------- persistent kernel (plain launch; 144 blocks, 1/CU) ----------
__global__ __launch_bounds__(256, 1) void k_fused(
        const float* __restrict__ x, const float* __restrict__ Wih,
        const float* __restrict__ Whh, const float* __restrict__ bih,
        const float* __restrict__ bhh, const float* __restrict__ Wif,
        const float* __restrict__ bif, const float* __restrict__ Wemb,
        const float* __restrict__ bemb, float* __restrict__ out,
        float* __restrict__ ws)
{
    __shared__ __align__(16) char smem_raw[(sizeof(SM) > sizeof(SA)) ? sizeof(SM) : sizeof(SA)];
    SA& sa = *reinterpret_cast<SA*>(smem_raw);
    SM& sm = *reinterpret_cast<SM*>(smem_raw);

    const int bid = blockIdx.x, tid = threadIdx.x;

    float* h0    = ws + OFF_H0;
    float* h1    = ws + OFF_H1;
    float* c     = ws + OFF_C;
    float* lr    = ws + OFF_LR;
    float* gmem  = ws + OFF_MEM;
    float* glink = ws + OFF_LINK;
    float* gprec = ws + OFF_PREC;
    float* grw   = ws + OFF_RW;
    float* gww   = ws + OFF_WW;
    float* gusg  = ws + OFF_USG;
    unsigned* flagA = (unsigned*)(ws + OFF_FLAGA);
    unsigned* flagC = (unsigned*)(ws + OFF_FLAGC);

    for (int t = 0; t < T_; ++t) {
        const float* hp = (t & 1) ? h1 : h0;
        float*       hn = (t & 1) ? h0 : h1;

        // phase A: gates (0..127) / out(t-1) (128..143)
        if (bid < 128)
            gates_body(sa, bid, tid, x, Wih, Whh, bih, bhh, hp, hn, c, lr, t);
        else if (t > 0)
            out_body(sa, bid, tid, Wemb, bemb, hp, lr, out, t - 1);
        post_flag(&flagA[bid * 32], (unsigned)(t + 1));

        // phase C: memory machine (blocks 0..31) — waits for all h + lr readers
        if (bid < 32) {
            wait_flags(flagA, NBLK, (unsigned)(t + 1));
            mem_body(sm, bid, tid, Wif, bif, hn,
                     gmem, glink, gprec, grw, gww, gusg, lr);
            post_flag(&flagC[bid * 32], (unsigned)(t + 1));
        }
        // everyone needs lr(t) / mem-state before next step
        wait_flags(flagC, 32, (unsigned)(t + 1));
    }

    // tail: out(T-1)
    if (bid >= 128) {
        const float* hfin = ((T_ - 1) & 1) ? h0 : h1;
        out_body(sa, bid, tid, Wemb, bemb, hfin, lr, out, T_ - 1);
    }
}

extern "C" void kernel_launch(void* const* d_in, const int* in_sizes, int n_in,
                              void* d_out, int out_size, void* d_ws, size_t ws_size,
                              hipStream_t stream)
{
    const float* x    = (const float*)d_in[0];
    const float* Wih  = (const float*)d_in[1];
    const float* Whh  = (const float*)d_in[2];
    const float* bih  = (const float*)d_in[3];
    const float* bhh  = (const float*)d_in[4];
    const float* Wif  = (const float*)d_in[5];
    const float* bif  = (const float*)d_in[6];
    const float* Wemb = (const float*)d_in[7];
    const float* bemb = (const float*)d_in[8];
    float* out = (float*)d_out;
    float* ws  = (float*)d_ws;

    k_init<<<512, 256, 0, stream>>>(ws, WS_TOTAL);

    k_fused<<<dim3(NBLK), dim3(256), 0, stream>>>(x, Wih, Whh, bih, bhh,
                                                  Wif, bif, Wemb, bemb, out, ws);
}

// Round 7
// 9001.386 us; speedup vs baseline: 2.3324x; 1.3597x over previous
//
#include <hip/hip_runtime.h>
#include <math.h>

#define B_    32
#define T_    128
#define IN_   256
#define H_    512
#define N_    128
#define R_    4
#define W_    64
#define RW_   256
#define FOUT_ 256
#define IF_   471
#define EPSF  1e-6f
#define KT_   256
#define KPAD  260
#define NBLK  176   // 128 gates + 16 out + 16 spare-out + 32 mem -> 0..127 gates, 128..143 out, 144..175 mem

// ---------- workspace layout (float offsets) ----------
#define OFF_H0    0
#define OFF_H1    (H_*B_)                // 16384
#define OFF_C     (2*H_*B_)              // 32768
#define OFF_LR    (3*H_*B_)              // 49152  (8192 floats)
#define OFF_FLAGA (OFF_LR + RW_*B_)      // 57344  (144*32 uints)
#define OFF_FLAGC (OFF_FLAGA + 144*32)   // +4608  (32*32 uints)
#define WS_TOTAL  (OFF_FLAGC + 32*32)

__device__ __forceinline__ float sig_(float x)   { return 1.0f / (1.0f + expf(-x)); }
__device__ __forceinline__ float splus_(float x) { return fmaxf(x, 0.0f) + log1pf(expf(-fabsf(x))); }

// ---------- coherent (agent-scope, sc1: bypass L2, served by IC) accessors ----------
__device__ __forceinline__ float cload(const float* p) {
    return __hip_atomic_load(p, __ATOMIC_RELAXED, __HIP_MEMORY_SCOPE_AGENT);
}
__device__ __forceinline__ void cstore(float* p, float v) {
    __hip_atomic_store(p, v, __ATOMIC_RELAXED, __HIP_MEMORY_SCOPE_AGENT);
}

__device__ __forceinline__ unsigned long long shflx64(unsigned long long v, int m) {
    unsigned int lo = (unsigned int)v, hi = (unsigned int)(v >> 32);
    lo = (unsigned int)__shfl_xor((int)lo, m);
    hi = (unsigned int)__shfl_xor((int)hi, m);
    return ((unsigned long long)hi << 32) | lo;
}

__global__ void k_init(float* p, int n) {
    for (int i = blockIdx.x * blockDim.x + threadIdx.x; i < n; i += gridDim.x * blockDim.x)
        p[i] = 0.0f;
}

// ---------- fence-free flag sync ----------
// All cross-block data moves via sc1 (write-through, L2-bypass) accesses, so no
// L2 writeback/invalidate is needed. Release = drain vmem (per wave) + barrier,
// then one relaxed flag store. Acquire = relaxed poll + block barrier.
__device__ __forceinline__ void post_flag(unsigned* slot, unsigned val) {
    asm volatile("s_waitcnt vmcnt(0)" ::: "memory");  // sc1 stores complete -> visible at IC
    __syncthreads();
    if (threadIdx.x == 0)
        __hip_atomic_store(slot, val, __ATOMIC_RELAXED, __HIP_MEMORY_SCOPE_AGENT);
}
__device__ __forceinline__ void wait_flags(unsigned* flags, int nf, unsigned val) {
    if ((int)threadIdx.x < nf) {
        while (__hip_atomic_load(&flags[threadIdx.x * 32], __ATOMIC_RELAXED,
                                 __HIP_MEMORY_SCOPE_AGENT) < val)
            __builtin_amdgcn_s_sleep(2);
    }
    __syncthreads();
}

// ---------- shared-memory overlays ----------
struct SA { float act[32 * KPAD]; float sg[4][4][32]; };
struct SM {               // persists across the whole T loop in mem blocks (~113 KB)
    float link[N_][N_ + 1];
    float mem[N_ * (W_ + 1)];
    float hb[H_];
    float rw[R_*N_], fwd[R_*N_], bwd[R_*N_], cr[R_*N_];
    float cw[N_], usage[N_], alloc[N_], wwv[N_], prc[N_], minv[N_];
    float rkeys[R_*W_], wkey[W_], ev[W_], wv[W_];
    float rstr[R_], fg[R_], kinv[R_], m1[R_], modes[R_*3], sc[8];
    unsigned long long key[N_];
};

// ---- stage a [256][32] tile from [k][b]-major source into lds[b][k], coherent ----
__device__ __forceinline__ void stage_kb_coh(const float* __restrict__ src, float* lds, int tid) {
    #pragma unroll
    for (int i = 0; i < 8; ++i) {
        int f = i * 256 + tid;            // float4 index
        int k = f >> 3;
        int b4 = (f & 7) << 2;
        float v0 = cload(src + 4*f + 0);
        float v1 = cload(src + 4*f + 1);
        float v2 = cload(src + 4*f + 2);
        float v3 = cload(src + 4*f + 3);
        lds[(b4 + 0) * KPAD + k] = v0;
        lds[(b4 + 1) * KPAD + k] = v1;
        lds[(b4 + 2) * KPAD + k] = v2;
        lds[(b4 + 3) * KPAD + k] = v3;
    }
}

__device__ __forceinline__ void stage_x(const float* __restrict__ x, int t, float* lds, int tid) {
    #pragma unroll
    for (int i = 0; i < 8; ++i) {
        int f = i * 256 + tid;
        int b  = f >> 6;
        int k4 = (f & 63) << 2;
        float4 v = *reinterpret_cast<const float4*>(x + ((size_t)b * T_ + t) * IN_ + k4);
        *reinterpret_cast<float4*>(&lds[b * KPAD + k4]) = v;
    }
}

__device__ __forceinline__ void tile_mac4(const float* lds,
        const float* __restrict__ w0p, const float* __restrict__ w1p,
        const float* __restrict__ w2p, const float* __restrict__ w3p,
        int lane, float* v)
{
    float4 w0 = *reinterpret_cast<const float4*>(w0p + lane * 4);
    float4 w1 = *reinterpret_cast<const float4*>(w1p + lane * 4);
    float4 w2 = *reinterpret_cast<const float4*>(w2p + lane * 4);
    float4 w3 = *reinterpret_cast<const float4*>(w3p + lane * 4);
    #pragma unroll
    for (int b = 0; b < 32; ++b) {
        float4 a = *reinterpret_cast<const float4*>(lds + b * KPAD + lane * 4);
        v[0*32+b] = fmaf(w0.w, a.w, fmaf(w0.z, a.z, fmaf(w0.y, a.y, fmaf(w0.x, a.x, v[0*32+b]))));
        v[1*32+b] = fmaf(w1.w, a.w, fmaf(w1.z, a.z, fmaf(w1.y, a.y, fmaf(w1.x, a.x, v[1*32+b]))));
        v[2*32+b] = fmaf(w2.w, a.w, fmaf(w2.z, a.z, fmaf(w2.y, a.y, fmaf(w2.x, a.x, v[2*32+b]))));
        v[3*32+b] = fmaf(w3.w, a.w, fmaf(w3.z, a.z, fmaf(w3.y, a.y, fmaf(w3.x, a.x, v[3*32+b]))));
    }
}

__device__ __forceinline__ void fold128(float* v, int lane) {
    #define FOLD_STAGE(D, HALF) { _Pragma("unroll") \
        for (int i = 0; i < HALF; ++i) { \
            float a_ = v[i], c_ = v[i + HALF]; \
            float t_ = (lane & D) ? a_ : c_; \
            t_ = __shfl_xor(t_, D); \
            v[i] = (lane & D) ? (c_ + t_) : (a_ + t_); } }
    FOLD_STAGE(32, 64) FOLD_STAGE(16, 32) FOLD_STAGE(8, 16)
    FOLD_STAGE(4, 8)   FOLD_STAGE(2, 4)   FOLD_STAGE(1, 2)
    #undef FOLD_STAGE
}

// ---------- phase bodies ----------
__device__ void gates_body(SA& sa, int bid, int tid,
        const float* __restrict__ x, const float* __restrict__ Wih,
        const float* __restrict__ Whh, const float* __restrict__ bih,
        const float* __restrict__ bhh,
        const float* __restrict__ hprev, float* __restrict__ hnew,
        float* __restrict__ c, const float* __restrict__ lr, int t)
{
    int lane = tid & 63, wid = tid >> 6;
    float v[128];
    #pragma unroll
    for (int i = 0; i < 128; ++i) v[i] = 0.0f;
    int j = bid * 4 + wid;
    for (int kt = 0; kt < 4; ++kt) {
        __syncthreads();
        if (kt == 0)      stage_x(x, t, sa.act, tid);
        else if (kt == 1) stage_kb_coh(lr, sa.act, tid);
        else              stage_kb_coh(hprev + (kt - 2) * KT_ * B_, sa.act, tid);
        __syncthreads();
        const float *w0, *w1, *w2, *w3;
        if (kt < 2) {
            w0 = Wih + ((size_t)(0*H_ + j)) * 512 + kt * 256;
            w1 = Wih + ((size_t)(1*H_ + j)) * 512 + kt * 256;
            w2 = Wih + ((size_t)(2*H_ + j)) * 512 + kt * 256;
            w3 = Wih + ((size_t)(3*H_ + j)) * 512 + kt * 256;
        } else {
            w0 = Whh + ((size_t)(0*H_ + j)) * 512 + (kt - 2) * 256;
            w1 = Whh + ((size_t)(1*H_ + j)) * 512 + (kt - 2) * 256;
            w2 = Whh + ((size_t)(2*H_ + j)) * 512 + (kt - 2) * 256;
            w3 = Whh + ((size_t)(3*H_ + j)) * 512 + (kt - 2) * 256;
        }
        tile_mac4(sa.act, w0, w1, w2, w3, lane, v);
    }
    fold128(v, lane);
    int r = (lane >> 4) & 3, b0 = (lane & 15) * 2;
    sa.sg[wid][r][b0]     = v[0];
    sa.sg[wid][r][b0 + 1] = v[1];
    __syncthreads();
    if (lane < 32) {
        int b = lane;
        float ai = sa.sg[wid][0][b] + bih[j]          + bhh[j];
        float af = sa.sg[wid][1][b] + bih[H_ + j]     + bhh[H_ + j];
        float ag = sa.sg[wid][2][b] + bih[2*H_ + j]   + bhh[2*H_ + j];
        float ao = sa.sg[wid][3][b] + bih[3*H_ + j]   + bhh[3*H_ + j];
        float ig = sig_(ai), fg = sig_(af), gg = tanhf(ag), og = sig_(ao);
        float cn = fg * c[j*B_ + b] + ig * gg;      // c is block-private: normal access
        c[j*B_ + b] = cn;
        cstore(&hnew[j*B_ + b], og * tanhf(cn));    // h is cross-block: coherent
    }
}

__device__ void out_body(SA& sa, int bid, int tid,
        const float* __restrict__ Wemb, const float* __restrict__ bemb,
        const float* __restrict__ hsrc, const float* __restrict__ lr,
        float* __restrict__ out, int tcol)
{
    int lane = tid & 63, wid = tid >> 6;
    float v[128];
    #pragma unroll
    for (int i = 0; i < 128; ++i) v[i] = 0.0f;
    int rowbase = (bid - 128) * 16 + wid * 4;
    for (int kt = 0; kt < 3; ++kt) {
        __syncthreads();
        if (kt < 2) stage_kb_coh(hsrc + kt * KT_ * B_, sa.act, tid);
        else        stage_kb_coh(lr, sa.act, tid);
        __syncthreads();
        const float* w0 = Wemb + (size_t)(rowbase + 0) * 768 + kt * 256;
        const float* w1 = Wemb + (size_t)(rowbase + 1) * 768 + kt * 256;
        const float* w2 = Wemb + (size_t)(rowbase + 2) * 768 + kt * 256;
        const float* w3 = Wemb + (size_t)(rowbase + 3) * 768 + kt * 256;
        tile_mac4(sa.act, w0, w1, w2, w3, lane, v);
    }
    fold128(v, lane);
    int rloc = (lane >> 4) & 3, b0 = (lane & 15) * 2;
    int row = rowbase + rloc;
    float bb = bemb[row];
    out[((size_t)b0       * T_ + tcol) * FOUT_ + row] = v[0] + bb;
    out[((size_t)(b0 + 1) * T_ + tcol) * FOUT_ + row] = v[1] + bb;
}

// memory machine for batch b; ALL state LDS-resident across steps.
__device__ void mem_body(SM& sm, int b, int tid,
        const float* __restrict__ Wif, const float* __restrict__ bif,
        const float* __restrict__ gh, float* __restrict__ glr)
{
    const int lane = tid & 63, wid = tid >> 6;

    // 0. stage h column (coherent)
    #pragma unroll
    for (int s = 0; s < 2; ++s) {
        int k = tid + s * 256;
        sm.hb[k] = cload(&gh[k*B_ + b]);
    }
    __syncthreads();

    // 1. xi GEMV (2 rows/thread, 4 chains) + parse
    #pragma unroll
    for (int s = 0; s < 2; ++s) {
        int i = tid + s * 256;
        if (i < IF_) {
            const float4* wr = reinterpret_cast<const float4*>(Wif + (size_t)i * H_);
            float a0 = 0.f, a1 = 0.f, a2 = 0.f, a3 = 0.f;
            #pragma unroll 8
            for (int q = 0; q < H_/4; ++q) {
                float4 w4 = wr[q];
                a0 = fmaf(w4.x, sm.hb[q*4+0], a0);
                a1 = fmaf(w4.y, sm.hb[q*4+1], a1);
                a2 = fmaf(w4.z, sm.hb[q*4+2], a2);
                a3 = fmaf(w4.w, sm.hb[q*4+3], a3);
            }
            float vv = (a0 + a1) + (a2 + a3) + bif[i];
            if      (i < 256) sm.rkeys[i]     = tanhf(vv);
            else if (i < 260) sm.rstr[i-256]  = splus_(vv);
            else if (i < 324) sm.wkey[i-260]  = tanhf(vv);
            else if (i < 325) sm.sc[0]        = splus_(vv);
            else if (i < 389) sm.ev[i-325]    = sig_(vv);
            else if (i < 453) sm.wv[i-389]    = tanhf(vv);
            else if (i < 457) sm.fg[i-453]    = sig_(vv);
            else if (i < 458) sm.sc[1]        = sig_(vv);
            else if (i < 459) sm.sc[2]        = sig_(vv);
            else              sm.modes[i-459] = vv;
        }
    }
    __syncthreads();

    // 2. usage update (LDS state), sort key, pre-update norms, head norms, modes softmax
    unsigned long long key = ~0ull;
    if (tid < N_) {
        float p = 1.0f;
        #pragma unroll
        for (int r = 0; r < R_; ++r) p *= 1.0f - sm.fg[r] * sm.rw[r*N_ + tid];
        float uo = sm.usage[tid], w0 = sm.wwv[tid];
        float u = (uo + w0 - uo*w0) * p;
        sm.usage[tid] = u;
        unsigned int fb = __float_as_uint(u);
        fb = (fb & 0x80000000u) ? ~fb : (fb | 0x80000000u);
        key = ((unsigned long long)fb << 32) | (unsigned int)tid;
        float s = 0.0f;
        for (int w = 0; w < W_; ++w) { float m = sm.mem[tid*(W_+1)+w]; s += m*m; }
        sm.minv[tid] = 1.0f / (sqrtf(s) + EPSF);
    }
    if (tid >= 128 && tid < 128 + R_) {
        int r = tid - 128;
        float s = 0.0f;
        for (int w = 0; w < W_; ++w) { float kv = sm.rkeys[r*W_+w]; s += kv*kv; }
        sm.kinv[r] = 1.0f / (sqrtf(s) + EPSF);
    }
    if (tid == 132) {
        float s = 0.0f;
        for (int w = 0; w < W_; ++w) s += sm.wkey[w]*sm.wkey[w];
        sm.sc[5] = 1.0f / (sqrtf(s) + EPSF);
    }
    if (tid >= 136 && tid < 136 + R_) {
        int r = tid - 136;
        float m0 = sm.modes[r*3], m1 = sm.modes[r*3+1], m2 = sm.modes[r*3+2];
        float mx = fmaxf(m0, fmaxf(m1, m2));
        float e0 = expf(m0-mx), e1 = expf(m1-mx), e2 = expf(m2-mx);
        float inv = 1.0f / (e0 + e1 + e2);
        sm.modes[r*3] = e0*inv; sm.modes[r*3+1] = e1*inv; sm.modes[r*3+2] = e2*inv;
    }
    __syncthreads();

    // 3. write-content dot, then register bitonic sort
    if (tid < N_) {
        float d = 0.0f;
        for (int w = 0; w < W_; ++w) d += sm.wkey[w] * sm.mem[tid*(W_+1)+w];
        sm.cw[tid] = d * sm.minv[tid] * sm.sc[5] * sm.sc[0];
    }
    for (int k = 2; k <= N_; k <<= 1) {
        for (int j = k >> 1; j > 0; j >>= 1) {
            unsigned long long pk;
            if (j == 64) {
                if (tid < N_) sm.key[tid] = key;
                __syncthreads();
                pk = (tid < N_) ? sm.key[tid ^ 64] : key;
                __syncthreads();
            } else {
                pk = shflx64(key, j);
            }
            bool lower = (tid & j) == 0;
            bool asc   = (tid & k) == 0;
            if ((key > pk) == (lower == asc)) key = pk;
        }
    }

    // 4. allocation via shfl product-scan; wave2 does write softmax
    float su = 0.0f, ex = 1.0f; int sidx = 0;
    if (tid < N_) {
        sidx = (int)(key & 0xffffffffu);
        su = sm.usage[sidx];
        float p = su;
        #pragma unroll
        for (int off = 1; off < 64; off <<= 1) {
            float pv = __shfl_up(p, off);
            if (lane >= off) p *= pv;
        }
        if (tid == 63) sm.sc[7] = p;
        float e = __shfl_up(p, 1);
        ex = (lane == 0) ? 1.0f : e;
    }
    __syncthreads();
    if (tid < N_) {
        if (tid >= 64) ex *= sm.sc[7];
        sm.alloc[sidx] = (1.0f - su) * ex;
    }
    if (wid == 2) {
        float v0 = sm.cw[lane], v1 = sm.cw[lane+64];
        float m = fmaxf(v0, v1);
        #pragma unroll
        for (int o = 32; o >= 1; o >>= 1) m = fmaxf(m, __shfl_xor(m, o));
        float e0 = expf(v0 - m), e1 = expf(v1 - m);
        float s = e0 + e1;
        #pragma unroll
        for (int o = 32; o >= 1; o >>= 1) s += __shfl_xor(s, o);
        sm.cw[lane] = e0; sm.cw[lane+64] = e1;
        if (lane == 0) sm.sc[4] = 1.0f / s;
    }
    __syncthreads();

    // 5. write weighting
    if (tid < N_) {
        float cwn = sm.cw[tid] * sm.sc[4];
        sm.wwv[tid] = sm.sc[2] * (sm.sc[1] * sm.alloc[tid] + (1.0f - sm.sc[1]) * cwn);
    }
    __syncthreads();

    // 6. memory update (LDS, in place) + sum_ww (wave3)
    for (int i = tid; i < N_*W_; i += 256) {
        int n = i >> 6, w = i & 63;
        float m = sm.mem[n*(W_+1)+w];
        sm.mem[n*(W_+1)+w] = m * (1.0f - sm.wwv[n]*sm.ev[w]) + sm.wwv[n]*sm.wv[w];
    }
    if (wid == 3) {
        float s = sm.wwv[lane] + sm.wwv[lane+64];
        #pragma unroll
        for (int o = 32; o >= 1; o >>= 1) s += __shfl_xor(s, o);
        if (lane == 0) sm.sc[6] = s;
    }
    __syncthreads();

    // 7. link update (LDS, in place)
    for (int i = tid; i < N_*N_; i += 256) {
        int row = i >> 7, col = i & 127;
        float wwr = sm.wwv[row];
        float nv = (1.0f - wwr - sm.wwv[col]) * sm.link[row][col] + wwr * sm.prc[col];
        if (row == col) nv = 0.0f;
        sm.link[row][col] = nv;
    }
    __syncthreads();

    // 7b. fwd/bwd as LDS dot products
    #pragma unroll
    for (int half = 0; half < 2; ++half) {
        int i = half * 256 + tid;         // (r, q)
        int r = i >> 7, q = i & 127;
        float accf = 0.0f, accb = 0.0f;
        #pragma unroll 4
        for (int m2 = 0; m2 < 128; ++m2) {
            float rv = sm.rw[r*N_ + m2];
            accf = fmaf(sm.link[q][m2], rv, accf);
            accb = fmaf(sm.link[m2][q], rv, accb);
        }
        sm.fwd[i] = accf;
        sm.bwd[i] = accb;
    }
    __syncthreads();

    // 8. precedence update + post-update norms
    if (tid < N_) {
        sm.prc[tid] = (1.0f - sm.sc[6]) * sm.prc[tid] + sm.wwv[tid];
        float s = 0.0f;
        for (int w = 0; w < W_; ++w) { float m = sm.mem[tid*(W_+1)+w]; s += m*m; }
        sm.minv[tid] = 1.0f / (sqrtf(s) + EPSF);
    }
    __syncthreads();

    // 9. read-content dots (post-update mem)
    for (int i = tid; i < R_*N_; i += 256) {
        int r = i >> 7, n = i & 127;
        float d = 0.0f;
        for (int w = 0; w < W_; ++w) d += sm.rkeys[r*W_+w] * sm.mem[n*(W_+1)+w];
        sm.cr[i] = d * sm.minv[n] * sm.kinv[r] * sm.rstr[r];
    }
    __syncthreads();

    // 10. per-head softmax (wave = head)
    {
        int r = wid;
        float v0 = sm.cr[r*N_ + lane], v1 = sm.cr[r*N_ + lane + 64];
        float m = fmaxf(v0, v1);
        #pragma unroll
        for (int o = 32; o >= 1; o >>= 1) m = fmaxf(m, __shfl_xor(m, o));
        float e0 = expf(v0 - m), e1 = expf(v1 - m);
        float s = e0 + e1;
        #pragma unroll
        for (int o = 32; o >= 1; o >>= 1) s += __shfl_xor(s, o);
        sm.cr[r*N_ + lane] = e0; sm.cr[r*N_ + lane + 64] = e1;
        if (lane == 0) sm.m1[r] = sm.modes[r*3+1] / s;
    }
    __syncthreads();

    // 11. new read weights (into persistent sm.rw)
    for (int i = tid; i < R_*N_; i += 256) {
        int r = i >> 7;
        sm.rw[i] = sm.modes[r*3] * sm.bwd[i] + sm.m1[r] * sm.cr[i] + sm.modes[r*3+2] * sm.fwd[i];
    }
    __syncthreads();

    // 12. read vectors -> last_read ([k][b], coherent)
    for (int i = tid; i < R_*W_; i += 256) {
        int r = i >> 6, w = i & 63;
        float d = 0.0f;
        for (int n = 0; n < N_; ++n) d += sm.rw[r*N_ + n] * sm.mem[n*(W_+1)+w];
        cstore(&glr[i*B_ + b], d);
    }
}

// ---------- persistent kernel: 176 blocks, 1/CU, roles disjoint ----------
__global__ __launch_bounds__(256, 1) void k_fused(
        const float* __restrict__ x, const float* __restrict__ Wih,
        const float* __restrict__ Whh, const float* __restrict__ bih,
        const float* __restrict__ bhh, const float* __restrict__ Wif,
        const float* __restrict__ bif, const float* __restrict__ Wemb,
        const float* __restrict__ bemb, float* __restrict__ out,
        float* __restrict__ ws)
{
    __shared__ __align__(16) char smem_raw[(sizeof(SM) > sizeof(SA)) ? sizeof(SM) : sizeof(SA)];
    SA& sa = *reinterpret_cast<SA*>(smem_raw);
    SM& sm = *reinterpret_cast<SM*>(smem_raw);

    const int bid = blockIdx.x, tid = threadIdx.x;

    float* h0 = ws + OFF_H0;
    float* h1 = ws + OFF_H1;
    float* c  = ws + OFF_C;
    float* lr = ws + OFF_LR;
    unsigned* flagA = (unsigned*)(ws + OFF_FLAGA);
    unsigned* flagC = (unsigned*)(ws + OFF_FLAGC);

    // mem blocks: zero-init LDS-resident state
    if (bid >= 144) {
        float* z = (float*)&sm;
        for (int i = tid; i < (int)(sizeof(SM)/4); i += 256) z[i] = 0.0f;
        __syncthreads();
    }

    for (int t = 0; t < T_; ++t) {
        const float* hp = (t & 1) ? h1 : h0;   // h(t-1)
        float*       hn = (t & 1) ? h0 : h1;   // h(t)

        if (bid < 128) {
            gates_body(sa, bid, tid, x, Wih, Whh, bih, bhh, hp, hn, c, lr, t);
            post_flag(&flagA[bid * 32], (unsigned)(t + 1));
            wait_flags(flagC, 32, (unsigned)(t + 1));
        } else if (bid < 144) {
            if (t > 0) out_body(sa, bid, tid, Wemb, bemb, hp, lr, out, t - 1);
            post_flag(&flagA[bid * 32], (unsigned)(t + 1));
            wait_flags(flagC, 32, (unsigned)(t + 1));
        } else {
            wait_flags(flagA, 144, (unsigned)(t + 1));
            mem_body(sm, bid - 144, tid, Wif, bif, hn, lr);
            post_flag(&flagC[(bid - 144) * 32], (unsigned)(t + 1));
        }
    }

    // tail: out(T-1) uses h(T-1) (= h0, since (T-1)&1 == 1) and lr(T-1)
    if (bid >= 128 && bid < 144) {
        out_body(sa, bid, tid, Wemb, bemb, h0, lr, out, T_ - 1);
    }
}

extern "C" void kernel_launch(void* const* d_in, const int* in_sizes, int n_in,
                              void* d_out, int out_size, void* d_ws, size_t ws_size,
                              hipStream_t stream)
{
    const float* x    = (const float*)d_in[0];
    const float* Wih  = (const float*)d_in[1];
    const float* Whh  = (const float*)d_in[2];
    const float* bih  = (const float*)d_in[3];
    const float* bhh  = (const float*)d_in[4];
    const float* Wif  = (const float*)d_in[5];
    const float* bif  = (const float*)d_in[6];
    const float* Wemb = (const float*)d_in[7];
    const float* bemb = (const float*)d_in[8];
    float* out = (float*)d_out;
    float* ws  = (float*)d_ws;

    k_init<<<64, 256, 0, stream>>>(ws, WS_TOTAL);

    k_fused<<<dim3(NBLK), dim3(256), 0, stream>>>(x, Wih, Whh, bih, bhh,
                                                  Wif, bif, Wemb, bemb, out, ws);
}